// Round 6
// baseline (396.865 us; speedup 1.0000x reference)
//
#include <hip/hip_runtime.h>
#include <math.h>

#define BB 32
#define DD 2048
#define NKVH 4
#define HDIM 128
#define MAXS 4096
#define FFD 8192
#define POS 4095
#define EPSV 1e-5f
#define SCALE 0.08838834764831845f
#define ASPLIT 32
#define SPOS 128   // positions per split

// workspace offsets (floats)
#define OFF_QT   0u        // 32 x 2048 q (NORMAL layout, atomic target)
#define OFF_KT   65536u    // 512 x 32 (transposed)
#define OFF_VT   81920u    // 512 x 32
#define OFF_G1   98304u    // 8192 x 32
#define OFF_G2   360448u   // 8192 x 32
#define ZERO_N   622592u   // contiguous atomic-target region [0, ZERO_N)
#define OFF_XAT  622592u   // 2048 x 32
#define OFF_PML  720896u   // 32*32*16 x {m,l} = 32768
#define OFF_PACC 753664u   // 32*32*16 x 128 = 2097152
#define OFF_YT   2850816u  // 2048 x 32
#define OFF_H    2916352u  // 32 x 2048 (normal)
#define OFF_XFT  2981888u  // 2048 x 32
#define OFF_KFIX 3047424u  // 32 x 16 x 512 (last-16-pos K records, pos 4095 patched)
#define OFF_VFIX 3309568u  // 32 x 16 x 512

#define VM_WAIT16 asm volatile("s_waitcnt vmcnt(16)" ::: "memory")
#define VM_WAIT8  asm volatile("s_waitcnt vmcnt(8)" ::: "memory")
#define VM_WAIT0  asm volatile("s_waitcnt vmcnt(0)" ::: "memory")
#define SCHED0    __builtin_amdgcn_sched_barrier(0)
#define SBAR      __builtin_amdgcn_s_barrier()

#define REP32(M) M(0) M(1) M(2) M(3) M(4) M(5) M(6) M(7) M(8) M(9) M(10) M(11) M(12) M(13) M(14) M(15) M(16) M(17) M(18) M(19) M(20) M(21) M(22) M(23) M(24) M(25) M(26) M(27) M(28) M(29) M(30) M(31)
#define REP32A(M,X) M(0,X) M(1,X) M(2,X) M(3,X) M(4,X) M(5,X) M(6,X) M(7,X) M(8,X) M(9,X) M(10,X) M(11,X) M(12,X) M(13,X) M(14,X) M(15,X) M(16,X) M(17,X) M(18,X) M(19,X) M(20,X) M(21,X) M(22,X) M(23,X) M(24,X) M(25,X) M(26,X) M(27,X) M(28,X) M(29,X) M(30,X) M(31,X)

#define DECLA(i) float a##i = 0.f;
#define FMA1(i,k) a##i = fmaf(ap[(k)*32 + (i)], w##k, a##i);
#define STORET(i) tl[i] = a##i;

// 32-batch GEMV, transposed output via LDS-staged coalesced atomics.
// C[n][b] += sum_d At[d][b] * W[d][n]. Used for the dual (kv, w12) paths.
template<int N, int CH>
__device__ __forceinline__ void gemv_body_t(const float* __restrict__ At,
                                            const float* __restrict__ W,
                                            float* __restrict__ C, int colblk,
                                            float* tile) {
    int tid = (int)threadIdx.x;
    int n = colblk * 256 + tid;
    int d0 = blockIdx.y * CH;
    const float* Wp = W + (size_t)d0 * N + n;
    const float* ap = At + (size_t)d0 * 32;
    REP32(DECLA)
#pragma unroll 4
    for (int dd = 0; dd < CH; dd += 4) {
        float w0 = Wp[0];
        float w1 = Wp[(size_t)N];
        float w2 = Wp[(size_t)N * 2];
        float w3 = Wp[(size_t)N * 3];
        REP32A(FMA1, 0)
        REP32A(FMA1, 1)
        REP32A(FMA1, 2)
        REP32A(FMA1, 3)
        Wp += (size_t)N * 4;
        ap += 128;
    }
    float* tl = tile + tid * 33;
    REP32(STORET)
    __syncthreads();
    float* cb = C + (size_t)colblk * 256 * 32;
#pragma unroll
    for (int i = 0; i < 32; ++i) {
        int f = i * 256 + tid;
        atomicAdd(cb + f, tile[(f >> 5) * 33 + (f & 31)]);
    }
}

template<int N, int CH, int HALF>
__global__ __launch_bounds__(256) void gemv32_dual_kernel(const float* __restrict__ At,
        const float* __restrict__ W0, const float* __restrict__ W1,
        float* __restrict__ C0, float* __restrict__ C1) {
    __shared__ float tile[256 * 33];
    int bx = blockIdx.x;
    if (bx < HALF) gemv_body_t<N, CH>(At, W0, C0, bx, tile);
    else           gemv_body_t<N, CH>(At, W1, C1, bx - HALF, tile);
}

// 2-col/thread GEMV, NORMAL-layout output with coalesced atomics.
// C[b][n..n+1] += sum_d At[d][b] * W[d][n..n+1]
#define DECL2(i) float2 a##i = {0.f, 0.f};
#define FMA2(i,k) { float av = ap[(k)*32 + (i)]; \
    a##i.x = fmaf(av, w##k.x, a##i.x); a##i.y = fmaf(av, w##k.y, a##i.y); }
#define ATOM2(i) atomicAdd(Cb + (size_t)(i)*N, a##i.x); \
                 atomicAdd(Cb + (size_t)(i)*N + 1, a##i.y);

template<int N, int CH>
__global__ __launch_bounds__(256) void gemv2_kernel(const float* __restrict__ At,
                                                    const float* __restrict__ W,
                                                    float* __restrict__ C) {
    int tid = (int)threadIdx.x;
    int n = blockIdx.x * 512 + tid * 2;
    int d0 = blockIdx.y * CH;
    const float* Wp = W + (size_t)d0 * N + n;
    const float* ap = At + (size_t)d0 * 32;
    REP32(DECL2)
#pragma unroll 4
    for (int dd = 0; dd < CH; dd += 4) {
        float2 w0 = *(const float2*)(Wp);
        float2 w1 = *(const float2*)(Wp + (size_t)N);
        float2 w2 = *(const float2*)(Wp + (size_t)N * 2);
        float2 w3 = *(const float2*)(Wp + (size_t)N * 3);
        REP32A(FMA2, 0)
        REP32A(FMA2, 1)
        REP32A(FMA2, 2)
        REP32A(FMA2, 3)
        Wp += (size_t)N * 4;
        ap += 128;
    }
    float* Cb = C + n;
    REP32(ATOM2)
}

__global__ void zero_kernel(float* __restrict__ p) {
    p[blockIdx.x * 256 + threadIdx.x] = 0.f;
}

// rmsnorm row b: outT[d][b] = norm; cpy[b][d] = raw input (residual)
__global__ void rmsnorm_kernel(const float* __restrict__ in, const float* __restrict__ g,
                               float* __restrict__ outT, float* __restrict__ cpy) {
    int b = blockIdx.x;
    int tid = threadIdx.x; // 256
    const float* row = in + b * DD;
    float v[8];
    float ss = 0.f;
#pragma unroll
    for (int i = 0; i < 8; ++i) { v[i] = row[tid + i * 256]; ss += v[i] * v[i]; }
#pragma unroll
    for (int off = 32; off; off >>= 1) ss += __shfl_xor(ss, off);
    __shared__ float red[4];
    if ((tid & 63) == 0) red[tid >> 6] = ss;
    __syncthreads();
    ss = red[0] + red[1] + red[2] + red[3];
    float scale = rsqrtf(ss * (1.f / DD) + EPSV);
#pragma unroll
    for (int i = 0; i < 8; ++i) {
        int idx = tid + i * 256;
        outT[(size_t)idx * 32 + b] = v[i] * g[idx] * scale;
        if (cpy) cpy[b * DD + idx] = v[i];
    }
}

// materialize last-16-position K/V records [b][16][512]; pos 4095 is roped
// on the fly from kT/vT (reference ropes BOTH k and v; cache never mutated).
__global__ void fixrope_kernel(const float* __restrict__ kc, const float* __restrict__ vc,
                               const float* __restrict__ kT, const float* __restrict__ vT,
                               const float* __restrict__ cosb, const float* __restrict__ sinb,
                               float* __restrict__ kfix, float* __restrict__ vfix) {
    int idx = blockIdx.x * 256 + threadIdx.x;  // 32*16*512 = 262144
    int b = idx >> 13, rem = idx & 8191;
    int pos = rem >> 9, col = rem & 511;
    int gpos = 4080 + pos;
    float kv, vv;
    if (gpos == POS) {
        int d = col & 127, i = d >> 1;
        float c = cosb[i], s = sinb[i];
        int colp = col & ~1;
        float k0 = kT[(size_t)colp * 32 + b], k1 = kT[(size_t)(colp + 1) * 32 + b];
        float v0 = vT[(size_t)colp * 32 + b], v1 = vT[(size_t)(colp + 1) * 32 + b];
        if (d & 1) { kv = k0 * s + k1 * c; vv = v0 * s + v1 * c; }
        else       { kv = k0 * c - k1 * s; vv = v0 * c - v1 * s; }
    } else {
        size_t o = ((size_t)(b * MAXS + gpos)) * 512 + col;
        kv = kc[o]; vv = vc[o];
    }
    kfix[idx] = kv; vfix[idx] = vv;
}

// attention: grid 1024 = (b, 32 splits of 128 pos), all 4 kvh per block.
// K/V staged via global_load_lds into a 3-deep ring (no VGPR cost); counted
// vmcnt(16) keeps TWO 32 KB tiles in flight at all times (never drains mid-loop).
// 16 tiles of 16 pos: t=0..7 K (QK scores), t=8..15 V (PV accumulate).
// QK: thread=(pos,head), q in 128 pre-rotated VGPRs (rotation -> the wave's 16
// distinct LDS rows hit distinct bank groups). PV: thread=(head,c16), contiguous.
__global__ __launch_bounds__(256, 1) void attn_stage_kernel(
    const float* __restrict__ qn, const float* __restrict__ kc, const float* __restrict__ vc,
    const float* __restrict__ kfix, const float* __restrict__ vfix,
    float* __restrict__ pml, float* __restrict__ pacc) {
    int split = blockIdx.x & 31, b = blockIdx.x >> 5;
    int tid = threadIdx.x, lane = tid & 63, wv = tid >> 6;
    __shared__ float kbuf[3][8192];   // 3 x 32 KB ring (16 pos x 4 kvh x 128)
    __shared__ float p_s[128][16];    // [pos][head] scores -> exp
    int qpos = tid >> 4, qhead = tid & 15;
    int qr = qpos * 4 + (qhead >> 2);          // LDS 512B-row id (0..63)
    int vh = tid >> 4, c16 = tid & 15, vkvh = vh >> 2;
    int t0 = split * SPOS;

    // q pre-rotated: qrot[j] = q[b][qhead*128 + ((j+qr)&31)*4 ..]
    float4 qrot[32];
#pragma unroll
    for (int j = 0; j < 32; ++j) {
        int g = (j + qr) & 31;
        qrot[j] = *(const float4*)(qn + (size_t)b * DD + qhead * HDIM + g * 4);
    }
    float4 av0 = {0, 0, 0, 0}, av1 = {0, 0, 0, 0};

    auto stage = [&](int t) {
        int s = t & 7;
        const float* base;
        if (t < 8) base = (split == 31 && s == 7) ? kfix + (size_t)b * 8192
                                                  : kc + ((size_t)b * MAXS + t0 + s * 16) * 512;
        else       base = (split == 31 && s == 7) ? vfix + (size_t)b * 8192
                                                  : vc + ((size_t)b * MAXS + t0 + s * 16) * 512;
        const float* g = base + wv * 2048 + lane * 4;   // per-lane global src
        float* l = &kbuf[t % 3][wv * 2048];             // wave-uniform LDS base
#pragma unroll
        for (int i = 0; i < 8; ++i)
            __builtin_amdgcn_global_load_lds(
                (const __attribute__((address_space(1))) void*)(g + i * 256),
                (__attribute__((address_space(3))) void*)(l + i * 256), 16, 0, 0);
    };

    stage(0); stage(1);
    for (int t = 0; t < 16; ++t) {
        if (t < 14) { stage(t + 2); VM_WAIT16; }
        else if (t == 14) { VM_WAIT8; }
        else { VM_WAIT0; }
        SCHED0; SBAR;
        if (t == 8) {
            // softmax: wave w handles heads 4w..4w+3 (same heads it uses in PV)
#pragma unroll
            for (int hh = 0; hh < 4; ++hh) {
                int h = wv * 4 + hh;
                float e0 = p_s[lane][h], e1 = p_s[lane + 64][h];
                float m = fmaxf(e0, e1);
#pragma unroll
                for (int off = 32; off; off >>= 1) m = fmaxf(m, __shfl_xor(m, off));
                e0 = __expf(e0 - m); e1 = __expf(e1 - m);
                p_s[lane][h] = e0; p_s[lane + 64][h] = e1;
                float l2 = e0 + e1;
#pragma unroll
                for (int off = 32; off; off >>= 1) l2 += __shfl_xor(l2, off);
                if (lane == 0) {
                    int idx = ((b * ASPLIT + split) * 16 + h) * 2;
                    pml[idx] = m; pml[idx + 1] = l2;
                }
            }
        }
        const float* kb = kbuf[t % 3];
        if (t < 8) {
            float4 acc = {0, 0, 0, 0};
            const float* rowp = kb + qr * 128;
#pragma unroll
            for (int j = 0; j < 32; ++j) {
                int g = (j + qr) & 31;
                float4 k4 = *(const float4*)(rowp + g * 4);
                acc.x = fmaf(k4.x, qrot[j].x, acc.x);
                acc.y = fmaf(k4.y, qrot[j].y, acc.y);
                acc.z = fmaf(k4.z, qrot[j].z, acc.z);
                acc.w = fmaf(k4.w, qrot[j].w, acc.w);
            }
            p_s[t * 16 + qpos][qhead] = (acc.x + acc.y + acc.z + acc.w) * SCALE;
        } else {
            int s = t - 8;
            const float* vrow = kb + vkvh * 128 + c16 * 4;
#pragma unroll
            for (int p = 0; p < 16; ++p) {
                float pw = p_s[s * 16 + p][vh];
                float4 v0 = *(const float4*)(vrow + p * 512);
                float4 v1 = *(const float4*)(vrow + p * 512 + 64);
                av0.x = fmaf(pw, v0.x, av0.x); av0.y = fmaf(pw, v0.y, av0.y);
                av0.z = fmaf(pw, v0.z, av0.z); av0.w = fmaf(pw, v0.w, av0.w);
                av1.x = fmaf(pw, v1.x, av1.x); av1.y = fmaf(pw, v1.y, av1.y);
                av1.z = fmaf(pw, v1.z, av1.z); av1.w = fmaf(pw, v1.w, av1.w);
            }
        }
        SCHED0; SBAR;
    }
    size_t pbase = ((size_t)(b * ASPLIT + split) * 16 + vh) * HDIM;
    *(float4*)(pacc + pbase + c16 * 4) = av0;
    *(float4*)(pacc + pbase + 64 + c16 * 4) = av1;
}

// combine split partials: grid 512 = (b, h), 128 threads; writes yT
__global__ void attn_combine_kernel(const float* __restrict__ pml,
                                    const float* __restrict__ pacc, float* __restrict__ yT) {
    int bid = blockIdx.x;
    int b = bid >> 4, h = bid & 15;
    int d = threadIdx.x;
    float M = -INFINITY;
#pragma unroll 8
    for (int s = 0; s < ASPLIT; ++s)
        M = fmaxf(M, pml[((b * ASPLIT + s) * 16 + h) * 2]);
    float denom = 0.f, acc = 0.f;
#pragma unroll 4
    for (int s = 0; s < ASPLIT; ++s) {
        int idx = (b * ASPLIT + s) * 16 + h;
        float e = __expf(pml[idx * 2] - M);
        denom += pml[idx * 2 + 1] * e;
        acc += e * pacc[(size_t)idx * HDIM + d];
    }
    yT[(size_t)(h * HDIM + d) * 32 + b] = acc / denom;
}

__global__ void silu_mul_kernel(float* __restrict__ g1, const float* __restrict__ g2) {
    int i = blockIdx.x * 256 + threadIdx.x; // 262144
    float a = g1[i], bb = g2[i];
    g1[i] = a * bb / (1.f + __expf(-a));
}

extern "C" void kernel_launch(void* const* d_in, const int* in_sizes, int n_in,
                              void* d_out, int out_size, void* d_ws, size_t ws_size,
                              hipStream_t stream) {
    (void)in_sizes; (void)n_in; (void)out_size; (void)ws_size;
    const float* x    = (const float*)d_in[0];
    const float* cosb = (const float*)d_in[1];
    const float* sinb = (const float*)d_in[2];
    const float* kc   = (const float*)d_in[3];
    const float* vc   = (const float*)d_in[4];
    const float* wra  = (const float*)d_in[5];
    const float* wq   = (const float*)d_in[6];
    const float* wk   = (const float*)d_in[7];
    const float* wv   = (const float*)d_in[8];
    const float* wo   = (const float*)d_in[9];
    const float* wrf  = (const float*)d_in[10];
    const float* w1   = (const float*)d_in[11];
    const float* w2   = (const float*)d_in[12];
    const float* w3   = (const float*)d_in[13];
    float* out = (float*)d_out;
    float* ws  = (float*)d_ws;

    float* qn   = ws + OFF_QT;
    float* kT   = ws + OFF_KT;
    float* vT   = ws + OFF_VT;
    float* g1T  = ws + OFF_G1;
    float* g2T  = ws + OFF_G2;
    float* xaT  = ws + OFF_XAT;
    float* pml  = ws + OFF_PML;
    float* pacc = ws + OFF_PACC;
    float* yT   = ws + OFF_YT;
    float* h    = ws + OFF_H;
    float* xfT  = ws + OFF_XFT;
    float* kfix = ws + OFF_KFIX;
    float* vfix = ws + OFF_VFIX;

    // zero all atomic-accumulated buffers (qn,kT,vT,g1,g2 contiguous)
    zero_kernel<<<ZERO_N / 256, 256, 0, stream>>>(ws);

    // xaT = rmsnorm(x)^T, h = x
    rmsnorm_kernel<<<32, 256, 0, stream>>>(x, wra, xaT, h);
    // q (NORMAL layout for attn register loads), k/v (transposed for rope)
    gemv2_kernel<2048, 32><<<dim3(4, 64), 256, 0, stream>>>(xaT, wq, qn);
    gemv32_dual_kernel<512, 32, 2><<<dim3(4, 64), 256, 0, stream>>>(xaT, wk, wv, kT, vT);
    // patched last-16 records with rope applied to pos 4095 (cache NOT mutated)
    fixrope_kernel<<<1024, 256, 0, stream>>>(kc, vc, kT, vT, cosb, sinb, kfix, vfix);
    // attention
    attn_stage_kernel<<<1024, 256, 0, stream>>>(qn, kc, vc, kfix, vfix, pml, pacc);
    attn_combine_kernel<<<512, 128, 0, stream>>>(pml, pacc, yT);
    // h = x + y @ wo
    gemv2_kernel<2048, 32><<<dim3(4, 64), 256, 0, stream>>>(yT, wo, h);
    // xfT = rmsnorm(h)^T, out = h
    rmsnorm_kernel<<<32, 256, 0, stream>>>(h, wrf, xfT, out);
    // g1 = xf@w1, g2 = xf@w2 (transposed outputs)
    gemv32_dual_kernel<8192, 128, 32><<<dim3(64, 16), 256, 0, stream>>>(xfT, w1, w2, g1T, g2T);
    // g1 = silu(g1)*g2 (elementwise, layout-agnostic)
    silu_mul_kernel<<<1024, 256, 0, stream>>>(g1T, g2T);
    // out += g1 @ w3
    gemv2_kernel<2048, 128><<<dim3(4, 64), 256, 0, stream>>>(g1T, w3, out);
}

// Round 7
// 304.249 us; speedup vs baseline: 1.3044x; 1.3044x over previous
//
#include <hip/hip_runtime.h>
#include <math.h>

#define BB 32
#define DD 2048
#define NKVH 4
#define HDIM 128
#define MAXS 4096
#define FFD 8192
#define POS 4095
#define EPSV 1e-5f
#define SCALE 0.08838834764831845f
#define ASPLIT 32
#define SPOS 128   // positions per split (32 per wave)

// workspace offsets (floats)
#define OFF_QT   0u        // 32 x 2048 q (NORMAL layout, atomic target)
#define OFF_KT   65536u    // 512 x 32 (transposed)
#define OFF_VT   81920u    // 512 x 32
#define OFF_G1   98304u    // 8192 x 32
#define OFF_G2   360448u   // 8192 x 32
#define ZERO_N   622592u   // contiguous atomic-target region [0, ZERO_N)
#define OFF_XAT  622592u   // 2048 x 32
#define OFF_PML  720896u   // 32*32*16 x {m,l}
#define OFF_PACC 753664u   // 32*32*16 x 128
#define OFF_YT   2850816u  // 2048 x 32
#define OFF_H    2916352u  // 32 x 2048 (normal)
#define OFF_XFT  2981888u  // 2048 x 32
#define OFF_KFIX 3047424u  // 32 x 16 x 512 (last-16-pos K records, pos 4095 patched)
#define OFF_VFIX 3309568u  // 32 x 16 x 512

#define VM_WAIT8  asm volatile("s_waitcnt vmcnt(8)" ::: "memory")
#define VM_WAIT0  asm volatile("s_waitcnt vmcnt(0)" ::: "memory")
#define SCHED0    __builtin_amdgcn_sched_barrier(0)

#define REP32(M) M(0) M(1) M(2) M(3) M(4) M(5) M(6) M(7) M(8) M(9) M(10) M(11) M(12) M(13) M(14) M(15) M(16) M(17) M(18) M(19) M(20) M(21) M(22) M(23) M(24) M(25) M(26) M(27) M(28) M(29) M(30) M(31)
#define REP32A(M,X) M(0,X) M(1,X) M(2,X) M(3,X) M(4,X) M(5,X) M(6,X) M(7,X) M(8,X) M(9,X) M(10,X) M(11,X) M(12,X) M(13,X) M(14,X) M(15,X) M(16,X) M(17,X) M(18,X) M(19,X) M(20,X) M(21,X) M(22,X) M(23,X) M(24,X) M(25,X) M(26,X) M(27,X) M(28,X) M(29,X) M(30,X) M(31,X)

#define DECLA(i) float a##i = 0.f;
#define FMA1(i,k) a##i = fmaf(ap[(k)*32 + (i)], w##k, a##i);
#define STORET(i) tl[i] = a##i;
#define ATOMN(i) atomicAdd(C + (size_t)(i)*N + n, a##i);

// 32-batch GEMV: C[b][n] += sum_d At[d][b] * W[d][n].
// TOUT: C transposed [N][32], staged via LDS, coalesced atomics.
template<int N, int CH, bool TOUT>
__device__ __forceinline__ void gemv_body(const float* __restrict__ At,
                                          const float* __restrict__ W,
                                          float* __restrict__ C, int colblk,
                                          float* tile) {
    int tid = (int)threadIdx.x;
    int n = colblk * 256 + tid;
    int d0 = blockIdx.y * CH;
    const float* Wp = W + (size_t)d0 * N + n;
    const float* ap = At + (size_t)d0 * 32;
    REP32(DECLA)
#pragma unroll 4
    for (int dd = 0; dd < CH; dd += 4) {
        float w0 = Wp[0];
        float w1 = Wp[(size_t)N];
        float w2 = Wp[(size_t)N * 2];
        float w3 = Wp[(size_t)N * 3];
        REP32A(FMA1, 0)
        REP32A(FMA1, 1)
        REP32A(FMA1, 2)
        REP32A(FMA1, 3)
        Wp += (size_t)N * 4;
        ap += 128;
    }
    if constexpr (TOUT) {
        float* tl = tile + tid * 33;
        REP32(STORET)
        __syncthreads();
        float* cb = C + (size_t)colblk * 256 * 32;
#pragma unroll
        for (int i = 0; i < 32; ++i) {
            int f = i * 256 + tid;
            atomicAdd(cb + f, tile[(f >> 5) * 33 + (f & 31)]);
        }
    } else {
        REP32(ATOMN)
    }
}

template<int N, int CH, bool TOUT>
__global__ __launch_bounds__(256) void gemv32_kernel(const float* __restrict__ At,
                                                     const float* __restrict__ W,
                                                     float* __restrict__ C) {
    if constexpr (TOUT) {
        __shared__ float tile[256 * 33];
        gemv_body<N, CH, true>(At, W, C, blockIdx.x, tile);
    } else {
        gemv_body<N, CH, false>(At, W, C, blockIdx.x, nullptr);
    }
}

template<int N, int CH, int HALF>
__global__ __launch_bounds__(256) void gemv32_dual_kernel(const float* __restrict__ At,
        const float* __restrict__ W0, const float* __restrict__ W1,
        float* __restrict__ C0, float* __restrict__ C1) {
    __shared__ float tile[256 * 33];
    int bx = blockIdx.x;
    if (bx < HALF) gemv_body<N, CH, true>(At, W0, C0, bx, tile);
    else           gemv_body<N, CH, true>(At, W1, C1, bx - HALF, tile);
}

__global__ void zero_kernel(float* __restrict__ p) {
    p[blockIdx.x * 256 + threadIdx.x] = 0.f;
}

// rmsnorm row b: outT[d][b] = norm; cpy[b][d] = raw input (residual)
__global__ void rmsnorm_kernel(const float* __restrict__ in, const float* __restrict__ g,
                               float* __restrict__ outT, float* __restrict__ cpy) {
    int b = blockIdx.x;
    int tid = threadIdx.x; // 256
    const float* row = in + b * DD;
    float v[8];
    float ss = 0.f;
#pragma unroll
    for (int i = 0; i < 8; ++i) { v[i] = row[tid + i * 256]; ss += v[i] * v[i]; }
#pragma unroll
    for (int off = 32; off; off >>= 1) ss += __shfl_xor(ss, off);
    __shared__ float red[4];
    if ((tid & 63) == 0) red[tid >> 6] = ss;
    __syncthreads();
    ss = red[0] + red[1] + red[2] + red[3];
    float scale = rsqrtf(ss * (1.f / DD) + EPSV);
#pragma unroll
    for (int i = 0; i < 8; ++i) {
        int idx = tid + i * 256;
        outT[(size_t)idx * 32 + b] = v[i] * g[idx] * scale;
        if (cpy) cpy[b * DD + idx] = v[i];
    }
}

// materialize last-16-position K/V records [b][16][512]; pos 4095 is roped
// on the fly from kT/vT (reference ropes BOTH k and v; cache never mutated).
__global__ void fixrope_kernel(const float* __restrict__ kc, const float* __restrict__ vc,
                               const float* __restrict__ kT, const float* __restrict__ vT,
                               const float* __restrict__ cosb, const float* __restrict__ sinb,
                               float* __restrict__ kfix, float* __restrict__ vfix) {
    int idx = blockIdx.x * 256 + threadIdx.x;  // 32*16*512 = 262144
    int b = idx >> 13, rem = idx & 8191;
    int pos = rem >> 9, col = rem & 511;
    int gpos = 4080 + pos;
    float kv, vv;
    if (gpos == POS) {
        int d = col & 127, i = d >> 1;
        float c = cosb[i], s = sinb[i];
        int colp = col & ~1;
        float k0 = kT[(size_t)colp * 32 + b], k1 = kT[(size_t)(colp + 1) * 32 + b];
        float v0 = vT[(size_t)colp * 32 + b], v1 = vT[(size_t)(colp + 1) * 32 + b];
        if (d & 1) { kv = k0 * s + k1 * c; vv = v0 * s + v1 * c; }
        else       { kv = k0 * c - k1 * s; vv = v0 * c - v1 * s; }
    } else {
        size_t o = ((size_t)(b * MAXS + gpos)) * 512 + col;
        kv = kc[o]; vv = vc[o];
    }
    kfix[idx] = kv; vfix[idx] = vv;
}

// Wave-autonomous attention: grid 1024 = (b, 32 splits of 128 pos).
// Each WAVE owns 32 positions: stages its own 8 KB (4-pos all-kvh) subtiles
// into a private double buffer via global_load_lds; vmcnt(8)-counted waits;
// ZERO barriers in the streaming loop (per-wave buffers -> no cross-wave
// hazards). Per-wave softmax (own max); cross-wave merge at the end via
// exp(m_w - M) scaling of register partials + 2 barriers total.
__global__ __launch_bounds__(256, 2) void attn_wave_kernel(
    const float* __restrict__ qn, const float* __restrict__ kc, const float* __restrict__ vc,
    const float* __restrict__ kfix, const float* __restrict__ vfix,
    float* __restrict__ pml, float* __restrict__ pacc) {
    int split = blockIdx.x & 31, b = blockIdx.x >> 5;
    int tid = threadIdx.x, w = tid >> 6, lane = tid & 63;
    __shared__ float kbuf[4][2][2048];   // [wave][dbuf][8 KB]
    __shared__ float p_s[128][16];       // [pos][head] scores -> exp
    __shared__ float m_s[4][16], l_s[4][16];
    int qpos = lane >> 4, qhead = lane & 15;
    int qr = lane >> 2;                  // row id (pos*4+kvh) in own 8 KB tile
    int c16 = lane & 15, vh0 = lane >> 4; // PV: heads vh0+4j, dims c16*4(+64)
    int t0 = split * SPOS;
    int wbase = w * 32;                  // wave's position offset within split

    // q pre-rotated so the wave's 16 distinct LDS rows hit distinct banks
    float4 qrot[32];
#pragma unroll
    for (int j = 0; j < 32; ++j) {
        int g = (j + qr) & 31;
        qrot[j] = *(const float4*)(qn + (size_t)b * DD + qhead * HDIM + g * 4);
    }
    float4 a[8];
#pragma unroll
    for (int k = 0; k < 8; ++k) a[k] = (float4){0, 0, 0, 0};

    auto stage = [&](int s) {            // s: 0..7 K subtile, 8..15 V subtile
        int sk = s & 7;
        int g0 = t0 + wbase + sk * 4;
        bool fix = (split == 31) && (w == 3) && (sk >= 4);
        const float* base;
        if (s < 8) base = fix ? kfix + (size_t)b * 8192 + (sk - 4) * 2048
                              : kc + ((size_t)b * MAXS + g0) * 512;
        else       base = fix ? vfix + (size_t)b * 8192 + (sk - 4) * 2048
                              : vc + ((size_t)b * MAXS + g0) * 512;
        const float* g = base + lane * 4;          // per-lane global src (16 B)
        float* l = &kbuf[w][s & 1][0];             // wave-uniform LDS base
#pragma unroll
        for (int i = 0; i < 8; ++i)
            __builtin_amdgcn_global_load_lds(
                (const __attribute__((address_space(1))) void*)(g + i * 256),
                (__attribute__((address_space(3))) void*)(l + i * 256), 16, 0, 0);
    };

    stage(0);
#pragma unroll 1
    for (int t = 0; t < 16; ++t) {
        if (t < 15) { stage(t + 1); VM_WAIT8; } else { VM_WAIT0; }
        SCHED0;
        const float* kb = &kbuf[w][t & 1][0];
        if (t < 8) {
            float4 acc = {0, 0, 0, 0};
            const float* rowp = kb + qr * 128;
#pragma unroll
            for (int j = 0; j < 32; ++j) {
                int g = (j + qr) & 31;
                float4 k4 = *(const float4*)(rowp + g * 4);
                acc.x = fmaf(k4.x, qrot[j].x, acc.x);
                acc.y = fmaf(k4.y, qrot[j].y, acc.y);
                acc.z = fmaf(k4.z, qrot[j].z, acc.z);
                acc.w = fmaf(k4.w, qrot[j].w, acc.w);
            }
            p_s[wbase + t * 4 + qpos][qhead] = (acc.x + acc.y + acc.z + acc.w) * SCALE;
            if (t == 7) {
                // per-wave softmax over its 32 pos x 16 heads (no barrier:
                // wave reads only its own p_s rows)
                int h = lane >> 2, sub = lane & 3;
                float v[8];
                float m = -INFINITY;
#pragma unroll
                for (int j = 0; j < 8; ++j) {
                    v[j] = p_s[wbase + sub * 8 + j][h];
                    m = fmaxf(m, v[j]);
                }
                m = fmaxf(m, __shfl_xor(m, 1));
                m = fmaxf(m, __shfl_xor(m, 2));
                float lsum = 0.f;
#pragma unroll
                for (int j = 0; j < 8; ++j) {
                    float e = __expf(v[j] - m);
                    p_s[wbase + sub * 8 + j][h] = e;
                    lsum += e;
                }
                lsum += __shfl_xor(lsum, 1);
                lsum += __shfl_xor(lsum, 2);
                if (sub == 0) { m_s[w][h] = m; l_s[w][h] = lsum; }
            }
        } else {
            int s = t - 8;
#pragma unroll
            for (int j = 0; j < 4; ++j) {        // kvh = j (wave-uniform read rows)
#pragma unroll
                for (int p = 0; p < 4; ++p) {
                    float pw = p_s[wbase + s * 4 + p][vh0 + 4 * j];
                    const float* vr = kb + p * 512 + j * 128 + c16 * 4;
                    float4 v0 = *(const float4*)(vr);
                    float4 v1 = *(const float4*)(vr + 64);
                    a[j * 2].x = fmaf(pw, v0.x, a[j * 2].x);
                    a[j * 2].y = fmaf(pw, v0.y, a[j * 2].y);
                    a[j * 2].z = fmaf(pw, v0.z, a[j * 2].z);
                    a[j * 2].w = fmaf(pw, v0.w, a[j * 2].w);
                    a[j * 2 + 1].x = fmaf(pw, v1.x, a[j * 2 + 1].x);
                    a[j * 2 + 1].y = fmaf(pw, v1.y, a[j * 2 + 1].y);
                    a[j * 2 + 1].z = fmaf(pw, v1.z, a[j * 2 + 1].z);
                    a[j * 2 + 1].w = fmaf(pw, v1.w, a[j * 2 + 1].w);
                }
            }
        }
    }
    __syncthreads();   // barrier 1: all m_s/l_s visible
    // rescale own partials to global per-head max
    float fac[4];
#pragma unroll
    for (int j = 0; j < 4; ++j) {
        int h = vh0 + 4 * j;
        float M = fmaxf(fmaxf(m_s[0][h], m_s[1][h]), fmaxf(m_s[2][h], m_s[3][h]));
        fac[j] = __expf(m_s[w][h] - M);
    }
#pragma unroll
    for (int j = 0; j < 4; ++j) {
        a[j * 2].x *= fac[j]; a[j * 2].y *= fac[j]; a[j * 2].z *= fac[j]; a[j * 2].w *= fac[j];
        a[j * 2 + 1].x *= fac[j]; a[j * 2 + 1].y *= fac[j]; a[j * 2 + 1].z *= fac[j]; a[j * 2 + 1].w *= fac[j];
    }
    if (w > 0) {       // dump scaled partials into own (now-free) kbuf region
        float* d = &kbuf[w][0][0];
#pragma unroll
        for (int k = 0; k < 8; ++k) *(float4*)(d + lane * 32 + k * 4) = a[k];
    }
    __syncthreads();   // barrier 2: dumps visible
    if (w == 0) {
#pragma unroll
        for (int wv2 = 1; wv2 < 4; ++wv2) {
            const float* d = &kbuf[wv2][0][0];
#pragma unroll
            for (int k = 0; k < 8; ++k) {
                float4 t4 = *(const float4*)(d + lane * 32 + k * 4);
                a[k].x += t4.x; a[k].y += t4.y; a[k].z += t4.z; a[k].w += t4.w;
            }
        }
        size_t pbase = ((size_t)(b * ASPLIT + split) * 16) * HDIM;
#pragma unroll
        for (int j = 0; j < 4; ++j) {
            int h = vh0 + 4 * j;
            *(float4*)(pacc + pbase + h * HDIM + c16 * 4) = a[j * 2];
            *(float4*)(pacc + pbase + h * HDIM + 64 + c16 * 4) = a[j * 2 + 1];
        }
        if (lane < 16) {
            int h = lane;
            float M = fmaxf(fmaxf(m_s[0][h], m_s[1][h]), fmaxf(m_s[2][h], m_s[3][h]));
            float L = l_s[0][h] * __expf(m_s[0][h] - M) + l_s[1][h] * __expf(m_s[1][h] - M)
                    + l_s[2][h] * __expf(m_s[2][h] - M) + l_s[3][h] * __expf(m_s[3][h] - M);
            int idx = ((b * ASPLIT + split) * 16 + h) * 2;
            pml[idx] = M; pml[idx + 1] = L;
        }
    }
}

// combine split partials: grid 512 = (b, h), 128 threads; writes yT
__global__ void attn_combine_kernel(const float* __restrict__ pml,
                                    const float* __restrict__ pacc, float* __restrict__ yT) {
    int bid = blockIdx.x;
    int b = bid >> 4, h = bid & 15;
    int d = threadIdx.x;
    float M = -INFINITY;
#pragma unroll 8
    for (int s = 0; s < ASPLIT; ++s)
        M = fmaxf(M, pml[((b * ASPLIT + s) * 16 + h) * 2]);
    float denom = 0.f, acc = 0.f;
#pragma unroll 4
    for (int s = 0; s < ASPLIT; ++s) {
        int idx = (b * ASPLIT + s) * 16 + h;
        float e = __expf(pml[idx * 2] - M);
        denom += pml[idx * 2 + 1] * e;
        acc += e * pacc[(size_t)idx * HDIM + d];
    }
    yT[(size_t)(h * HDIM + d) * 32 + b] = acc / denom;
}

__global__ void silu_mul_kernel(float* __restrict__ g1, const float* __restrict__ g2) {
    int i = blockIdx.x * 256 + threadIdx.x; // 262144
    float a = g1[i], bb = g2[i];
    g1[i] = a * bb / (1.f + __expf(-a));
}

extern "C" void kernel_launch(void* const* d_in, const int* in_sizes, int n_in,
                              void* d_out, int out_size, void* d_ws, size_t ws_size,
                              hipStream_t stream) {
    (void)in_sizes; (void)n_in; (void)out_size; (void)ws_size;
    const float* x    = (const float*)d_in[0];
    const float* cosb = (const float*)d_in[1];
    const float* sinb = (const float*)d_in[2];
    const float* kc   = (const float*)d_in[3];
    const float* vc   = (const float*)d_in[4];
    const float* wra  = (const float*)d_in[5];
    const float* wq   = (const float*)d_in[6];
    const float* wk   = (const float*)d_in[7];
    const float* wv   = (const float*)d_in[8];
    const float* wo   = (const float*)d_in[9];
    const float* wrf  = (const float*)d_in[10];
    const float* w1   = (const float*)d_in[11];
    const float* w2   = (const float*)d_in[12];
    const float* w3   = (const float*)d_in[13];
    float* out = (float*)d_out;
    float* ws  = (float*)d_ws;

    float* qn   = ws + OFF_QT;
    float* kT   = ws + OFF_KT;
    float* vT   = ws + OFF_VT;
    float* g1T  = ws + OFF_G1;
    float* g2T  = ws + OFF_G2;
    float* xaT  = ws + OFF_XAT;
    float* pml  = ws + OFF_PML;
    float* pacc = ws + OFF_PACC;
    float* yT   = ws + OFF_YT;
    float* h    = ws + OFF_H;
    float* xfT  = ws + OFF_XFT;
    float* kfix = ws + OFF_KFIX;
    float* vfix = ws + OFF_VFIX;

    // zero all atomic-accumulated buffers (qn,kT,vT,g1,g2 contiguous)
    zero_kernel<<<ZERO_N / 256, 256, 0, stream>>>(ws);

    // xaT = rmsnorm(x)^T, h = x
    rmsnorm_kernel<<<32, 256, 0, stream>>>(x, wra, xaT, h);
    // q (NORMAL layout), k/v (transposed for rope)
    gemv32_kernel<2048, 32, false><<<dim3(8, 64), 256, 0, stream>>>(xaT, wq, qn);
    gemv32_dual_kernel<512, 32, 2><<<dim3(4, 64), 256, 0, stream>>>(xaT, wk, wv, kT, vT);
    // patched last-16 records with rope applied to pos 4095 (cache NOT mutated)
    fixrope_kernel<<<1024, 256, 0, stream>>>(kc, vc, kT, vT, cosb, sinb, kfix, vfix);
    // attention (wave-autonomous, barrier-free streaming)
    attn_wave_kernel<<<1024, 256, 0, stream>>>(qn, kc, vc, kfix, vfix, pml, pacc);
    attn_combine_kernel<<<512, 128, 0, stream>>>(pml, pacc, yT);
    // h = x + y @ wo
    gemv32_kernel<2048, 32, false><<<dim3(8, 64), 256, 0, stream>>>(yT, wo, h);
    // xfT = rmsnorm(h)^T, out = h
    rmsnorm_kernel<<<32, 256, 0, stream>>>(h, wrf, xfT, out);
    // g1 = xf@w1, g2 = xf@w2 (transposed outputs)
    gemv32_dual_kernel<8192, 128, 32><<<dim3(64, 16), 256, 0, stream>>>(xfT, w1, w2, g1T, g2T);
    // g1 = silu(g1)*g2 (elementwise, layout-agnostic)
    silu_mul_kernel<<<1024, 256, 0, stream>>>(g1T, g2T);
    // out += g1 @ w3
    gemv32_kernel<2048, 128, false><<<dim3(8, 64), 256, 0, stream>>>(g1T, w3, out);
}